// Round 19
// baseline (39874.808 us; speedup 1.0000x reference)
//
#include <hip/hip_runtime.h>
#include <math.h>

#define BB 32
#define TENC 200
#define NMELS 80
#define TMELS 400
#define STEPS 200
#define MEM 256
#define PRE1N 256
#define PRE2N 128
#define AD 128
#define DK 21
#define DF 8
#define SK 21
#define SF 8
#define PL 11
#define BLK 1024

// ushort offsets in ws:
#define QW1 0u         // LSTM1 weights [4][1024][160] bf16 (K=640: ctx|pre|h1)
#define QW2 655360u    // LSTM2 weights [4][1024][192] bf16 (K=768: h1|ctx|h2)
#define HP5 1441792u   // ac_W [64][160][8] bf16 (end 1523712 ushorts)
// float offsets:
#define WS_ATTWT 761856u   // att_W^T [256][128]
#define WS_ATTVT 794624u   // att_V^T [128][168]
#define WS_PW1T  816128u   // pre_W1^T [80][256]
#define WS_PW2T  836608u   // pre_W2^T [256][128]
#define WS_PRE2  869376u   // prenet out [200][32][128]

// dynamic-LDS float offsets
#define L_XS   0      // 768: activation concat
#define L_H1   768
#define L_C1   1024
#define L_H2   1280
#define L_C2   1536
#define L_CTX  1792
#define L_AL   2048   // 200
#define L_PS   2248   // 200
#define L_ES   2448   // 200
#define L_P4   2656   // 4096 partials (aliased: LSTM partials / q-partials / ctx partials)
#define L_QS   6752   // 128
#define L_GS   6880   // 168
#define L_FS   7048   // 1600
#define L_WF   8648   // 168
#define L_PR   8816   // 11
#define L_RB   8828   // 17
#define L_B1   8848   // 1024
#define L_B2   9872   // 1024
#define L_AW   10896  // att_W^T bf16: 32768 ushorts = 16384 floats
#define DYNF   27280
#define DYNB   (DYNF*4)

__device__ __forceinline__ float sigm(float x){ return 1.f/(1.f+expf(-x)); }
__device__ __forceinline__ float tanh_fast(float x){
  float ax = fabsf(x);
  float z = __expf(-2.f*ax);
  float r = (1.f - z)/(1.f + z);
  return (x < 0.f) ? -r : r;
}

// FMA of 8 bf16 weights (uint4) against 8 activations (two float4) into one acc
#define FMA8S(wv, xa, xb, acc) \
  acc += __uint_as_float((wv).x<<16)*(xa).x + __uint_as_float((wv).x&0xffff0000u)*(xa).y \
       + __uint_as_float((wv).y<<16)*(xa).z + __uint_as_float((wv).y&0xffff0000u)*(xa).w \
       + __uint_as_float((wv).z<<16)*(xb).x + __uint_as_float((wv).z&0xffff0000u)*(xb).y \
       + __uint_as_float((wv).w<<16)*(xb).z + __uint_as_float((wv).w&0xffff0000u)*(xb).w;

__device__ __forceinline__ unsigned short to_bf16(float f){
  unsigned u = __float_as_uint(f);
  return (unsigned short)((u + 0x7fffu + ((u>>16)&1u)) >> 16);
}

// transpose: src[R][C] -> dst[C][R]
__global__ __launch_bounds__(256) void trk(const float* __restrict__ s, float* __restrict__ d, int R, int C){
  int i = blockIdx.x*256 + threadIdx.x;
  if (i < R*C){ int r = i / C, c = i - r*C; d[c*R + r] = s[i]; }
}

// LSTM1 quarter-pack: K=640 = al_Wih cols(384) | al_Whh cols(256); quarter=160
__global__ __launch_bounds__(256) void pkq1(const float* __restrict__ wih, const float* __restrict__ whh,
                                            unsigned short* __restrict__ d){
  int i = blockIdx.x*256 + threadIdx.x;
  if (i < 1024*640){
    int c = i / 640, k = i - c*640;
    float v = (k < 384) ? wih[c*384 + k] : whh[c*256 + (k-384)];
    int q = k / 160, r = k - 160*q;
    d[((unsigned)(q*1024 + c))*160u + r] = to_bf16(v);
  }
}
// LSTM2 quarter-pack: K=768 = dl_Wih cols(512) | dl_Whh cols(256); quarter=192
__global__ __launch_bounds__(256) void pkq2(const float* __restrict__ wih, const float* __restrict__ whh,
                                            unsigned short* __restrict__ d){
  int i = blockIdx.x*256 + threadIdx.x;
  if (i < 1024*768){
    int c = i / 768, k = i - c*768;
    float v = (k < 512) ? wih[c*512 + k] : whh[c*256 + (k-512)];
    int q = k / 192, r = k - 192*q;
    d[((unsigned)(q*1024 + c))*192u + r] = to_bf16(v);
  }
}
// 8-wide-pack (for ac_W): src[R][C] -> dst[(c>>3)*R*8 + r*8 + (c&7)]
__global__ __launch_bounds__(256) void pk8h(const float* __restrict__ s, unsigned short* __restrict__ d, int R, int C){
  int i = blockIdx.x*256 + threadIdx.x;
  if (i < R*C){ int r = i / C, c = i - r*C; d[(unsigned)(c>>3)*(unsigned)R*8u + (unsigned)r*8u + (c&7)] = to_bf16(s[i]); }
}

// prenet for all 200 steps (proven)
__global__ __launch_bounds__(256) void prenetk(const float* __restrict__ mels,
    const float* __restrict__ b1, const float* __restrict__ b2, float* __restrict__ ws){
  int t = blockIdx.x, tid = threadIdx.x;
  __shared__ float xS[BB*NMELS];
  __shared__ float p1S[BB*PRE1N];
  const float* W1T = ws + WS_PW1T;
  const float* W2T = ws + WS_PW2T;
  for (int i=tid;i<BB*NMELS;i+=256){
    int r = i/NMELS, k = i - r*NMELS;
    xS[i] = (t==0)?0.f : mels[r*NMELS*TMELS + k*TMELS + (2*t-1)];
  }
  __syncthreads();
  {
    float acc[BB];
    #pragma unroll
    for (int r=0;r<BB;r++) acc[r]=0.f;
    for (int k=0;k<NMELS;k++){
      float w = W1T[k*PRE1N + tid];
      #pragma unroll
      for (int r=0;r<BB;r++) acc[r] += xS[r*NMELS+k]*w;
    }
    float bb = b1[tid];
    #pragma unroll
    for (int r=0;r<BB;r++) p1S[r*PRE1N+tid] = fmaxf(acc[r]+bb, 0.f);
  }
  __syncthreads();
  if (tid < PRE2N){
    float acc[BB];
    #pragma unroll
    for (int r=0;r<BB;r++) acc[r]=0.f;
    for (int k=0;k<PRE1N;k++){
      float w = W2T[k*PRE2N + tid];
      #pragma unroll
      for (int r=0;r<BB;r++) acc[r] += p1S[r*PRE1N+k]*w;
    }
    float bb = b2[tid];
    #pragma unroll
    for (int r=0;r<BB;r++) ws[WS_PRE2 + ((unsigned)t*BB + r)*PRE2N + tid] = fmaxf(acc[r]+bb, 0.f);
  }
}

// ONE BLOCK PER BATCH. k-split x4 GEMVs; attW^T bf16 in LDS; uniform tensors via scalar cache.
__global__ __launch_bounds__(BLK) void decoder(
    const float* __restrict__ albih, const float* __restrict__ albhh,
    const float* __restrict__ dlbih, const float* __restrict__ dlbhh,
    const float* __restrict__ prior, const float* __restrict__ attF,
    const float* __restrict__ attWb, const float* __restrict__ attU,
    const float* __restrict__ attT, const float* __restrict__ attTb,
    const float* __restrict__ attv, const float* __restrict__ memory,
    const float* __restrict__ acb, const float* __restrict__ ws,
    float* __restrict__ out){
  extern __shared__ float sm[];
  const int b = blockIdx.x, tid = threadIdx.x;
  unsigned short* aWh = (unsigned short*)(sm + L_AW);
  const unsigned* aWu = (const unsigned*)(sm + L_AW);

  // ---- one-time init ----
  if (tid < 256){ sm[L_H1+tid]=0.f; sm[L_C1+tid]=0.f; sm[L_H2+tid]=0.f; sm[L_C2+tid]=0.f; sm[L_CTX+tid]=0.f; }
  if (tid < TENC) sm[L_AL+tid] = (tid==0)?1.f:0.f;
  sm[L_B1+tid] = albih[tid] + albhh[tid];
  sm[L_B2+tid] = dlbih[tid] + dlbhh[tid];
  if (tid < SF*SK) sm[L_WF+tid] = attF[tid];
  if (tid < PL)    sm[L_PR+tid] = prior[tid];
  for (int i = tid; i < 32768; i += BLK) aWh[i] = to_bf16(ws[WS_ATTWT + i]);
  __syncthreads();

  const unsigned short* hw = (const unsigned short*)ws;
  const unsigned short* Q1 = hw + QW1;
  const unsigned short* Q2 = hw + QW2;
  const unsigned short* P5 = hw + HP5;
  const float* attVT = ws + WS_ATTVT;
  const float acbv = (tid < 640) ? acb[tid >> 2] : 0.f;
  const int q = tid >> 8, c0 = tid & 255;

  for (int t = 0; t < STEPS; ++t){
    // 1. xS = [ctx 256 | pre 128 | h1 256]
    if (tid < 256) sm[L_XS+tid] = sm[L_CTX+tid];
    else if (tid < 384) sm[L_XS+tid] = __builtin_nontemporal_load(&ws[WS_PRE2 + ((unsigned)t*BB + b)*PRE2N + (tid-256)]);
    else if (tid < 640) sm[L_XS+tid] = sm[L_H1 + (tid-384)];
    __syncthreads();
    // 2. LSTM1 partials: quarter q (160 k), columns c0 + 256j
    {
      const float* xq = sm + L_XS + 160*q;
      const unsigned short* w0p = Q1 + ((unsigned)(q*1024 + c0      ))*160u;
      const unsigned short* w1p = Q1 + ((unsigned)(q*1024 + c0 + 256))*160u;
      const unsigned short* w2p = Q1 + ((unsigned)(q*1024 + c0 + 512))*160u;
      const unsigned short* w3p = Q1 + ((unsigned)(q*1024 + c0 + 768))*160u;
      float a0=0.f, a1=0.f, a2=0.f, a3=0.f;
      #pragma unroll 4
      for (int kk = 0; kk < 20; kk++){
        float4 xa = *(const float4*)(xq + 8*kk);
        float4 xb = *(const float4*)(xq + 8*kk + 4);
        uint4 w0 = *(const uint4*)(w0p + kk*8);
        uint4 w1 = *(const uint4*)(w1p + kk*8);
        uint4 w2 = *(const uint4*)(w2p + kk*8);
        uint4 w3 = *(const uint4*)(w3p + kk*8);
        FMA8S(w0, xa, xb, a0)
        FMA8S(w1, xa, xb, a1)
        FMA8S(w2, xa, xb, a2)
        FMA8S(w3, xa, xb, a3)
      }
      sm[L_P4 + q*1024 + c0      ] = a0;
      sm[L_P4 + q*1024 + c0 + 256] = a1;
      sm[L_P4 + q*1024 + c0 + 512] = a2;
      sm[L_P4 + q*1024 + c0 + 768] = a3;
    }
    __syncthreads();
    // 3. LSTM1 gates + state update
    if (tid < 256){
      float g[4];
      #pragma unroll
      for (int gg2 = 0; gg2 < 4; gg2++){
        int col = gg2*256 + tid;
        g[gg2] = sm[L_B1+col] + sm[L_P4+col] + sm[L_P4+1024+col] + sm[L_P4+2048+col] + sm[L_P4+3072+col];
      }
      float c = sigm(g[1])*sm[L_C1+tid] + sigm(g[0])*tanhf(g[2]);
      sm[L_C1+tid] = c;
      sm[L_H1+tid] = sigm(g[3])*tanhf(c);
    }
    __syncthreads();
    // 4. q-partials (tid<512, attW^T bf16 in LDS) || prior+static convs (tid in [512,712))
    if (tid < 512){
      const int quarter = tid >> 7, a = tid & 127;
      const int sel = a & 1, au = a >> 1;
      float s = 0.f;
      for (int k = 64*quarter; k < 64*quarter+64; k++){
        unsigned u = aWu[k*64 + au];
        float wv = __uint_as_float(sel ? (u & 0xffff0000u) : (u << 16));
        s += sm[L_H1+k]*wv;
      }
      sm[L_P4 + tid] = s;
    } else if (tid < 512+TENC){
      const int pos = tid - 512;
      float s = 0.f;
      #pragma unroll
      for (int jj = 0; jj < PL; jj++){ int qq = pos - jj; if (qq >= 0) s += sm[L_PR+jj]*sm[L_AL+qq]; }
      sm[L_PS+pos] = logf(fmaxf(s, 1e-6f));
      #pragma unroll
      for (int c = 0; c < SF; c++){
        float s2 = 0.f;
        #pragma unroll
        for (int k = 0; k < SK; k++){ int qq = pos + k - 10; if (qq>=0 && qq<TENC) s2 += sm[L_WF+c*SK+k]*sm[L_AL+qq]; }
        sm[L_FS + c*TENC + pos] = s2;
      }
    }
    __syncthreads();
    // 5. q = tanh
    if (tid < AD) sm[L_QS+tid] = tanhf(attWb[tid] + sm[L_P4+tid] + sm[L_P4+128+tid] + sm[L_P4+256+tid] + sm[L_P4+384+tid]);
    __syncthreads();
    // 6. G = attV @ q
    if (tid < DF*DK){
      float a = 0.f;
      for (int k = 0; k < AD; k++) a += sm[L_QS+k]*attVT[k*(DF*DK) + tid];
      sm[L_GS+tid] = a;
    }
    __syncthreads();
    // 7. e[pos] (4 threads/pos); attU/attT/attTb/attv uniform -> scalar cache
    if (tid < 4*TENC){
      const int pos = tid >> 2, qr = tid & 3;
      float g[DF];
      #pragma unroll
      for (int c=0;c<DF;c++){
        float s=0.f;
        #pragma unroll
        for (int k=0;k<DK;k++){
          int q2 = pos + k - 10;
          if (q2>=0 && q2<TENC) s += sm[L_AL+q2]*sm[L_GS+c*DK+k];
        }
        g[c]=s;
      }
      float fv[SF];
      #pragma unroll
      for (int s2=0;s2<SF;s2++) fv[s2] = sm[L_FS + s2*TENC + pos];
      float pp = 0.f;
      for (int h = qr*32; h < qr*32+32; h++){
        float u = attTb[h];
        #pragma unroll
        for (int s2=0;s2<SF;s2++) u += attU[h*SF+s2]*fv[s2];
        #pragma unroll
        for (int c=0;c<DF;c++) u += attT[h*DF+c]*g[c];
        pp += attv[h]*tanh_fast(u);
      }
      pp += __shfl_xor(pp,1);
      pp += __shfl_xor(pp,2);
      if (qr==0) sm[L_ES+pos] = pp + sm[L_PS+pos];
    }
    __syncthreads();
    // 8. softmax over 200
    float ex;
    {
      float v = (tid<TENC)? sm[L_ES+tid] : -3.0e38f;
      for (int o=1;o<64;o<<=1) v = fmaxf(v, __shfl_xor(v,o));
      if ((tid&63)==0) sm[L_RB+(tid>>6)] = v;
      __syncthreads();
      if (tid==0){ sm[L_RB+16] = fmaxf(fmaxf(sm[L_RB],sm[L_RB+1]), fmaxf(sm[L_RB+2],sm[L_RB+3])); }
      __syncthreads();
      float m = sm[L_RB+16];
      ex = (tid<TENC)? expf(sm[L_ES+tid]-m) : 0.f;
      float sv = ex;
      for (int o=1;o<64;o<<=1) sv += __shfl_xor(sv,o);
      __syncthreads();
      if ((tid&63)==0) sm[L_RB+(tid>>6)] = sv;
      __syncthreads();
      if (tid==0){ sm[L_RB+16] = 1.f/(sm[L_RB]+sm[L_RB+1]+sm[L_RB+2]+sm[L_RB+3]); }
      __syncthreads();
      float inv = sm[L_RB+16];
      if (tid<TENC){
        float a = ex*inv;
        sm[L_AL+tid] = a;
        out[1024000 + b*TENC*STEPS + tid*STEPS + t] = a;
      }
    }
    __syncthreads();
    // 9. ctx partials (nontemporal memory reads)
    {
      int grp = tid >> 8, j = tid & 255;
      float a0=0.f,a1=0.f;
      const float* mb = memory + (unsigned)b*TENC*MEM + j;
      for (int p=grp*50; p<grp*50+50; p+=2){
        a0 += sm[L_AL+p  ]*__builtin_nontemporal_load(&mb[(p  )*MEM]);
        a1 += sm[L_AL+p+1]*__builtin_nontemporal_load(&mb[(p+1)*MEM]);
      }
      sm[L_P4 + grp*256 + j] = a0+a1;
    }
    __syncthreads();
    // 9b. ctx reduce + build xS2 = [h1 | ctx | h2]
    if (tid < 256){
      float c = sm[L_P4+tid]+sm[L_P4+256+tid]+sm[L_P4+512+tid]+sm[L_P4+768+tid];
      sm[L_CTX+tid] = c;
      sm[L_XS+256+tid] = c;
    } else if (tid < 512){
      sm[L_XS + (tid-256)] = sm[L_H1 + (tid-256)];
    } else if (tid < 768){
      sm[L_XS + tid] = sm[L_H2 + (tid-512)];   // xS[512+i] = h2[i]  (FIXED)
    }
    __syncthreads();
    // 10. LSTM2 partials: quarter q (192 k), columns c0 + 256j
    {
      const float* xq = sm + L_XS + 192*q;
      const unsigned short* w0p = Q2 + ((unsigned)(q*1024 + c0      ))*192u;
      const unsigned short* w1p = Q2 + ((unsigned)(q*1024 + c0 + 256))*192u;
      const unsigned short* w2p = Q2 + ((unsigned)(q*1024 + c0 + 512))*192u;
      const unsigned short* w3p = Q2 + ((unsigned)(q*1024 + c0 + 768))*192u;
      float a0=0.f, a1=0.f, a2=0.f, a3=0.f;
      #pragma unroll 4
      for (int kk = 0; kk < 24; kk++){
        float4 xa = *(const float4*)(xq + 8*kk);
        float4 xb = *(const float4*)(xq + 8*kk + 4);
        uint4 w0 = *(const uint4*)(w0p + kk*8);
        uint4 w1 = *(const uint4*)(w1p + kk*8);
        uint4 w2 = *(const uint4*)(w2p + kk*8);
        uint4 w3 = *(const uint4*)(w3p + kk*8);
        FMA8S(w0, xa, xb, a0)
        FMA8S(w1, xa, xb, a1)
        FMA8S(w2, xa, xb, a2)
        FMA8S(w3, xa, xb, a3)
      }
      sm[L_P4 + q*1024 + c0      ] = a0;
      sm[L_P4 + q*1024 + c0 + 256] = a1;
      sm[L_P4 + q*1024 + c0 + 512] = a2;
      sm[L_P4 + q*1024 + c0 + 768] = a3;
    }
    __syncthreads();
    // 11. LSTM2 gates + state update
    if (tid < 256){
      float g[4];
      #pragma unroll
      for (int gg2 = 0; gg2 < 4; gg2++){
        int col = gg2*256 + tid;
        g[gg2] = sm[L_B2+col] + sm[L_P4+col] + sm[L_P4+1024+col] + sm[L_P4+2048+col] + sm[L_P4+3072+col];
      }
      float c = sigm(g[1])*sm[L_C2+tid] + sigm(g[0])*tanhf(g[2]);
      sm[L_C2+tid] = c;
      sm[L_H2+tid] = sigm(g[3])*tanhf(c);
    }
    __syncthreads();
    // 12. acoustic projection: 4 threads / col over K=512 [h2,ctx]
    if (tid < 640){
      const int col = tid >> 2, qq = tid & 3;
      float a0 = 0.f;
      #pragma unroll 4
      for (int kk = qq*16; kk < qq*16+16; kk++){
        uint4 wv = *(const uint4*)(P5 + (unsigned)kk*1280u + col*8u);
        const float* xp = (kk < 32) ? (sm + L_H2 + 8*kk) : (sm + L_CTX + 8*kk - 256);
        float4 xa = *(const float4*)(xp);
        float4 xb = *(const float4*)(xp + 4);
        FMA8S(wv, xa, xb, a0)
      }
      float acc = a0;
      acc += __shfl_xor(acc,1);
      acc += __shfl_xor(acc,2);
      if (qq==0){
        const int m = col >> 1, r = col & 1;
        out[(unsigned)b*NMELS*TMELS + m*TMELS + 2*t + r] = acc + acbv;
      }
    }
    __syncthreads();
  }
}

extern "C" void kernel_launch(void* const* d_in, const int* in_sizes, int n_in,
                              void* d_out, int out_size, void* d_ws, size_t ws_size,
                              hipStream_t stream) {
  (void)in_sizes; (void)n_in; (void)out_size; (void)ws_size;
  const float* mels   = (const float*)d_in[0];
  const float* memory = (const float*)d_in[1];
  const float* pre_W1 = (const float*)d_in[2];
  const float* pre_b1 = (const float*)d_in[3];
  const float* pre_W2 = (const float*)d_in[4];
  const float* pre_b2 = (const float*)d_in[5];
  const float* al_Wih = (const float*)d_in[6];
  const float* al_Whh = (const float*)d_in[7];
  const float* al_bih = (const float*)d_in[8];
  const float* al_bhh = (const float*)d_in[9];
  const float* att_W  = (const float*)d_in[10];
  const float* att_Wb = (const float*)d_in[11];
  const float* att_V  = (const float*)d_in[12];
  const float* att_F  = (const float*)d_in[13];
  const float* att_U  = (const float*)d_in[14];
  const float* att_T  = (const float*)d_in[15];
  const float* att_Tb = (const float*)d_in[16];
  const float* att_v  = (const float*)d_in[17];
  const float* prior  = (const float*)d_in[18];
  const float* dl_Wih = (const float*)d_in[19];
  const float* dl_Whh = (const float*)d_in[20];
  const float* dl_bih = (const float*)d_in[21];
  const float* dl_bhh = (const float*)d_in[22];
  const float* ac_W   = (const float*)d_in[23];
  const float* ac_b   = (const float*)d_in[24];
  float* ws  = (float*)d_ws;
  unsigned short* hw = (unsigned short*)d_ws;
  float* out = (float*)d_out;

  hipFuncSetAttribute((const void*)decoder, hipFuncAttributeMaxDynamicSharedMemorySize, DYNB);

  auto TR = [&](const float* src, unsigned off, int R, int C){
    int n = R*C;
    trk<<<dim3((n+255)/256), dim3(256), 0, stream>>>(src, ws + off, R, C);
  };
  pkq1<<<dim3((1024*640+255)/256), dim3(256), 0, stream>>>(al_Wih, al_Whh, hw + QW1);
  pkq2<<<dim3((1024*768+255)/256), dim3(256), 0, stream>>>(dl_Wih, dl_Whh, hw + QW2);
  pk8h<<<dim3((160*512+255)/256), dim3(256), 0, stream>>>(ac_W, hw + HP5, 160, 512);
  TR(att_W,  WS_ATTWT, 128, 256);
  TR(att_V,  WS_ATTVT, 168, 128);
  TR(pre_W1, WS_PW1T,  256, 80);
  TR(pre_W2, WS_PW2T,  128, 256);

  prenetk<<<dim3(STEPS), dim3(256), 0, stream>>>(mels, pre_b1, pre_b2, ws);

  decoder<<<dim3(BB), dim3(BLK), DYNB, stream>>>(
      al_bih, al_bhh, dl_bih, dl_bhh, prior, att_F,
      att_Wb, att_U, att_T, att_Tb, att_v, memory,
      ac_b, ws, out);
}

// Round 20
// 29874.487 us; speedup vs baseline: 1.3347x; 1.3347x over previous
//
#include <hip/hip_runtime.h>
#include <math.h>

#define BB 32
#define TENC 200
#define NMELS 80
#define TMELS 400
#define STEPS 200
#define MEM 256
#define PRE1N 256
#define PRE2N 128
#define AD 128
#define DK 21
#define DF 8
#define SK 21
#define SF 8
#define PL 11
#define BLK 1024

// ushort offsets (8-wide bf16 packs, r17 layout: elem(k,col) at (k>>3)*R*8 + col*8 + (k&7)):
#define HP1 0u          // al_Wih [48][1024][8] (K=384)
#define HP2 393216u     // al_Whh [32][1024][8]
#define HP3 655360u     // dl_Wih [64][1024][8]
#define HP4 1179648u    // dl_Whh [32][1024][8]
#define HP5 1441792u    // ac_W  [64][160][8]   end 1523712 ushorts
// float offsets:
#define WS_ATTWT 761856u   // att_W^T fp32 [256][128] (staged to LDS bf16 once)
#define WS_PW1T  816128u   // pre_W1^T [80][256]
#define WS_PW2T  836608u   // pre_W2^T [256][128]
#define WS_PRE2  869376u   // prenet out [200][32][128] fp32, end 1688576
#define WS_MEMH  1688576u  // memory bf16 [32][200][256] ushorts (819200 floats), end 2507776
#define WS_AVTH  2507776u  // att_V^T bf16 [128][168] ushorts (10752 floats), end 2518528
// total 10.07 MB

// dynamic-LDS float offsets
#define L_XS   0      // 128: prenet slice
#define L_H1   768
#define L_C1   1024
#define L_H2   1280
#define L_C2   1536
#define L_CTX  1792
#define L_AL   2048   // 200
#define L_PS   2248   // 200
#define L_ES   2448   // 200
#define L_P4   2656   // 4096: gat / q-partials / ctx partials (time-aliased)
#define L_QS   6752   // 128
#define L_GS   6880   // 168
#define L_FS   7048   // 1600
#define L_WF   8648   // 168
#define L_PR   8816   // 11
#define L_RB   8828   // 17
#define L_AW   10896  // att_W^T bf16: 32768 ushorts = 16384 floats
#define DYNF   27280
#define DYNB   (DYNF*4)

__device__ __forceinline__ float sigm(float x){ return 1.f/(1.f+expf(-x)); }
__device__ __forceinline__ float tanh_fast(float x){
  float ax = fabsf(x);
  float z = __expf(-2.f*ax);
  float r = (1.f - z)/(1.f + z);
  return (x < 0.f) ? -r : r;
}
__device__ __forceinline__ unsigned short to_bf16(float f){
  unsigned u = __float_as_uint(f);
  return (unsigned short)((u + 0x7fffu + ((u>>16)&1u)) >> 16);
}

// r17 FMA: 8 bf16 weights (uint4) against xp[0..7] into 4 accumulators
#define FMA8(wv, xp, a0, a1, a2, a3) \
  a0 += __uint_as_float((wv).x << 16)*(xp)[0] + __uint_as_float((wv).x & 0xffff0000u)*(xp)[1]; \
  a1 += __uint_as_float((wv).y << 16)*(xp)[2] + __uint_as_float((wv).y & 0xffff0000u)*(xp)[3]; \
  a2 += __uint_as_float((wv).z << 16)*(xp)[4] + __uint_as_float((wv).z & 0xffff0000u)*(xp)[5]; \
  a3 += __uint_as_float((wv).w << 16)*(xp)[6] + __uint_as_float((wv).w & 0xffff0000u)*(xp)[7];

// transpose: src[R][C] -> dst[C][R]
__global__ __launch_bounds__(256) void trk(const float* __restrict__ s, float* __restrict__ d, int R, int C){
  int i = blockIdx.x*256 + threadIdx.x;
  if (i < R*C){ int r = i / C, c = i - r*C; d[c*R + r] = s[i]; }
}
// 8-wide bf16 pack: src[R][C] -> dst[(c>>3)*R*8 + r*8 + (c&7)]
__global__ __launch_bounds__(256) void pk8h(const float* __restrict__ s, unsigned short* __restrict__ d, int R, int C){
  int i = blockIdx.x*256 + threadIdx.x;
  if (i < R*C){ int r = i / C, c = i - r*C; d[(unsigned)(c>>3)*(unsigned)R*8u + (unsigned)r*8u + (c&7)] = to_bf16(s[i]); }
}
// elementwise bf16 copy (memory)
__global__ __launch_bounds__(256) void pkmem(const float* __restrict__ s, unsigned short* __restrict__ d, int n){
  int i = blockIdx.x*256 + threadIdx.x;
  if (i < n) d[i] = to_bf16(s[i]);
}
// att_V^T bf16: d[k*168+a] = bf16(attV[a*128+k])
__global__ __launch_bounds__(256) void pkavt(const float* __restrict__ s, unsigned short* __restrict__ d){
  int i = blockIdx.x*256 + threadIdx.x;
  if (i < 128*168){ int k = i/168, a = i - k*168; d[i] = to_bf16(s[a*128 + k]); }
}

// prenet for all 200 steps (proven)
__global__ __launch_bounds__(256) void prenetk(const float* __restrict__ mels,
    const float* __restrict__ b1, const float* __restrict__ b2, float* __restrict__ ws){
  int t = blockIdx.x, tid = threadIdx.x;
  __shared__ float xS[BB*NMELS];
  __shared__ float p1S[BB*PRE1N];
  const float* W1T = ws + WS_PW1T;
  const float* W2T = ws + WS_PW2T;
  for (int i=tid;i<BB*NMELS;i+=256){
    int r = i/NMELS, k = i - r*NMELS;
    xS[i] = (t==0)?0.f : mels[r*NMELS*TMELS + k*TMELS + (2*t-1)];
  }
  __syncthreads();
  {
    float acc[BB];
    #pragma unroll
    for (int r=0;r<BB;r++) acc[r]=0.f;
    for (int k=0;k<NMELS;k++){
      float w = W1T[k*PRE1N + tid];
      #pragma unroll
      for (int r=0;r<BB;r++) acc[r] += xS[r*NMELS+k]*w;
    }
    float bb = b1[tid];
    #pragma unroll
    for (int r=0;r<BB;r++) p1S[r*PRE1N+tid] = fmaxf(acc[r]+bb, 0.f);
  }
  __syncthreads();
  if (tid < PRE2N){
    float acc[BB];
    #pragma unroll
    for (int r=0;r<BB;r++) acc[r]=0.f;
    for (int k=0;k<PRE1N;k++){
      float w = W2T[k*PRE2N + tid];
      #pragma unroll
      for (int r=0;r<BB;r++) acc[r] += p1S[r*PRE1N+k]*w;
    }
    float bb = b2[tid];
    #pragma unroll
    for (int r=0;r<BB;r++) ws[WS_PRE2 + ((unsigned)t*BB + r)*PRE2N + tid] = fmaxf(acc[r]+bb, 0.f);
  }
}

// ONE BLOCK PER BATCH. r17 coalesced GEMVs; attW^T bf16 LDS; bf16 memory/attV^T; scalar-cache uniforms.
__global__ __launch_bounds__(BLK) void decoder(
    const float* __restrict__ albih, const float* __restrict__ albhh,
    const float* __restrict__ dlbih, const float* __restrict__ dlbhh,
    const float* __restrict__ prior, const float* __restrict__ attF,
    const float* __restrict__ attWb, const float* __restrict__ attU,
    const float* __restrict__ attT, const float* __restrict__ attTb,
    const float* __restrict__ attv,
    const float* __restrict__ acb, const float* __restrict__ ws,
    float* __restrict__ out){
  extern __shared__ float sm[];
  const int b = blockIdx.x, tid = threadIdx.x;
  unsigned short* aWh = (unsigned short*)(sm + L_AW);
  const unsigned* aWu = (const unsigned*)(sm + L_AW);

  // ---- one-time init ----
  if (tid < 256){ sm[L_H1+tid]=0.f; sm[L_C1+tid]=0.f; sm[L_H2+tid]=0.f; sm[L_C2+tid]=0.f; sm[L_CTX+tid]=0.f; }
  if (tid < TENC) sm[L_AL+tid] = (tid==0)?1.f:0.f;
  if (tid < SF*SK) sm[L_WF+tid] = attF[tid];
  if (tid < PL)    sm[L_PR+tid] = prior[tid];
  for (int i = tid; i < 32768; i += BLK) aWh[i] = to_bf16(ws[WS_ATTWT + i]);
  __syncthreads();

  const unsigned short* hw = (const unsigned short*)ws;
  const unsigned short* P1 = hw + HP1;
  const unsigned short* P2 = hw + HP2;
  const unsigned short* P3 = hw + HP3;
  const unsigned short* P4 = hw + HP4;
  const unsigned short* P5 = hw + HP5;
  const unsigned* memh = (const unsigned*)(ws + WS_MEMH);
  const unsigned short* avth = (const unsigned short*)(ws + WS_AVTH);
  const float bias1 = albih[tid] + albhh[tid];
  const float bias2 = dlbih[tid] + dlbhh[tid];
  const float acbv  = (tid < 640) ? acb[tid >> 2] : 0.f;

  for (int t = 0; t < STEPS; ++t){
    // 1. stage prenet slice (streaming -> nontemporal)
    if (tid < 128) sm[L_XS+tid] = __builtin_nontemporal_load(&ws[WS_PRE2 + ((unsigned)t*BB + b)*PRE2N + tid]);
    __syncthreads();
    // 2. LSTM1 gates: K = [ctx 256 | pre 128] (P1) + h1 256 (P2)  — coalesced uint4
    {
      float a0 = bias1, a1 = 0.f, a2 = 0.f, a3 = 0.f;
      #pragma unroll 4
      for (int kk = 0; kk < 32; kk++){
        uint4 wv = *(const uint4*)(P1 + (unsigned)kk*8192u + tid*8u);
        const float* xp = sm + L_CTX + 8*kk;
        FMA8(wv, xp, a0, a1, a2, a3)
      }
      #pragma unroll 4
      for (int kk = 32; kk < 48; kk++){
        uint4 wv = *(const uint4*)(P1 + (unsigned)kk*8192u + tid*8u);
        const float* xp = sm + L_XS + 8*kk - 256;
        FMA8(wv, xp, a0, a1, a2, a3)
      }
      #pragma unroll 4
      for (int kk = 0; kk < 32; kk++){
        uint4 wv = *(const uint4*)(P2 + (unsigned)kk*8192u + tid*8u);
        const float* xp = sm + L_H1 + 8*kk;
        FMA8(wv, xp, a0, a1, a2, a3)
      }
      sm[L_P4+tid] = (a0+a1)+(a2+a3);
    }
    __syncthreads();
    // 3. LSTM1 state update
    if (tid < 256){
      float gi=sm[L_P4+tid], gf=sm[L_P4+256+tid], gg=sm[L_P4+512+tid], go=sm[L_P4+768+tid];
      float c = sigm(gf)*sm[L_C1+tid] + sigm(gi)*tanhf(gg);
      sm[L_C1+tid] = c;
      sm[L_H1+tid] = sigm(go)*tanhf(c);
    }
    __syncthreads();
    // 4. q-partials (tid<512, attW^T bf16 in LDS) || prior+static convs (tid in [512,712))
    if (tid < 512){
      const int quarter = tid >> 7, a = tid & 127;
      const int sel = a & 1, au = a >> 1;
      float s = 0.f;
      for (int k = 64*quarter; k < 64*quarter+64; k++){
        unsigned u = aWu[k*64 + au];
        float wv = __uint_as_float(sel ? (u & 0xffff0000u) : (u << 16));
        s += sm[L_H1+k]*wv;
      }
      sm[L_P4 + tid] = s;
    } else if (tid < 512+TENC){
      const int pos = tid - 512;
      float s = 0.f;
      #pragma unroll
      for (int jj = 0; jj < PL; jj++){ int qq = pos - jj; if (qq >= 0) s += sm[L_PR+jj]*sm[L_AL+qq]; }
      sm[L_PS+pos] = logf(fmaxf(s, 1e-6f));
      #pragma unroll
      for (int c = 0; c < SF; c++){
        float s2 = 0.f;
        #pragma unroll
        for (int k = 0; k < SK; k++){ int qq = pos + k - 10; if (qq>=0 && qq<TENC) s2 += sm[L_WF+c*SK+k]*sm[L_AL+qq]; }
        sm[L_FS + c*TENC + pos] = s2;
      }
    }
    __syncthreads();
    // 5. q = tanh
    if (tid < AD) sm[L_QS+tid] = tanhf(attWb[tid] + sm[L_P4+tid] + sm[L_P4+128+tid] + sm[L_P4+256+tid] + sm[L_P4+384+tid]);
    __syncthreads();
    // 6. G = attV @ q  (attV^T bf16 from global/L2)
    if (tid < DF*DK){
      float a = 0.f;
      for (int k = 0; k < AD; k++) a += sm[L_QS+k]*__uint_as_float(((unsigned)avth[k*(DF*DK)+tid])<<16);
      sm[L_GS+tid] = a;
    }
    __syncthreads();
    // 7. e[pos] (4 threads/pos); attU/attT/attTb/attv uniform -> scalar cache
    if (tid < 4*TENC){
      const int pos = tid >> 2, qr = tid & 3;
      float g[DF];
      #pragma unroll
      for (int c=0;c<DF;c++){
        float s=0.f;
        #pragma unroll
        for (int k=0;k<DK;k++){
          int q2 = pos + k - 10;
          if (q2>=0 && q2<TENC) s += sm[L_AL+q2]*sm[L_GS+c*DK+k];
        }
        g[c]=s;
      }
      float fv[SF];
      #pragma unroll
      for (int s2=0;s2<SF;s2++) fv[s2] = sm[L_FS + s2*TENC + pos];
      float pp = 0.f;
      for (int h = qr*32; h < qr*32+32; h++){
        float u = attTb[h];
        #pragma unroll
        for (int s2=0;s2<SF;s2++) u += attU[h*SF+s2]*fv[s2];
        #pragma unroll
        for (int c=0;c<DF;c++) u += attT[h*DF+c]*g[c];
        pp += attv[h]*tanh_fast(u);
      }
      pp += __shfl_xor(pp,1);
      pp += __shfl_xor(pp,2);
      if (qr==0) sm[L_ES+pos] = pp + sm[L_PS+pos];
    }
    __syncthreads();
    // 8. softmax over 200
    float ex;
    {
      float v = (tid<TENC)? sm[L_ES+tid] : -3.0e38f;
      for (int o=1;o<64;o<<=1) v = fmaxf(v, __shfl_xor(v,o));
      if ((tid&63)==0) sm[L_RB+(tid>>6)] = v;
      __syncthreads();
      if (tid==0){ sm[L_RB+16] = fmaxf(fmaxf(sm[L_RB],sm[L_RB+1]), fmaxf(sm[L_RB+2],sm[L_RB+3])); }
      __syncthreads();
      float m = sm[L_RB+16];
      ex = (tid<TENC)? expf(sm[L_ES+tid]-m) : 0.f;
      float sv = ex;
      for (int o=1;o<64;o<<=1) sv += __shfl_xor(sv,o);
      __syncthreads();
      if ((tid&63)==0) sm[L_RB+(tid>>6)] = sv;
      __syncthreads();
      if (tid==0){ sm[L_RB+16] = 1.f/(sm[L_RB]+sm[L_RB+1]+sm[L_RB+2]+sm[L_RB+3]); }
      __syncthreads();
      float inv = sm[L_RB+16];
      if (tid<TENC){
        float a = ex*inv;
        sm[L_AL+tid] = a;
        out[1024000 + b*TENC*STEPS + tid*STEPS + t] = a;
      }
    }
    __syncthreads();
    // 9. ctx partials: bf16 memory, cached (8 groups x 25 p, 128 column-pairs)
    {
      const int grp2 = tid >> 7, jp = tid & 127;
      const unsigned base = ((unsigned)b*TENC)*128u + jp;
      float a0 = 0.f, a1 = 0.f;
      for (int p = grp2*25; p < grp2*25+25; p++){
        unsigned u = memh[base + (unsigned)p*128u];
        float al = sm[L_AL+p];
        a0 += al*__uint_as_float(u << 16);
        a1 += al*__uint_as_float(u & 0xffff0000u);
      }
      sm[L_P4 + grp2*256 + 2*jp    ] = a0;
      sm[L_P4 + grp2*256 + 2*jp + 1] = a1;
    }
    __syncthreads();
    if (tid < 256){
      float c = 0.f;
      #pragma unroll
      for (int g2 = 0; g2 < 8; g2++) c += sm[L_P4 + g2*256 + tid];
      sm[L_CTX+tid] = c;
    }
    __syncthreads();
    // 10. LSTM2 gates: K = [h1 256 | ctx 256] (P3) + h2 256 (P4)
    {
      float a0 = bias2, a1 = 0.f, a2 = 0.f, a3 = 0.f;
      #pragma unroll 4
      for (int kk = 0; kk < 32; kk++){
        uint4 wv = *(const uint4*)(P3 + (unsigned)kk*8192u + tid*8u);
        const float* xp = sm + L_H1 + 8*kk;
        FMA8(wv, xp, a0, a1, a2, a3)
      }
      #pragma unroll 4
      for (int kk = 32; kk < 64; kk++){
        uint4 wv = *(const uint4*)(P3 + (unsigned)kk*8192u + tid*8u);
        const float* xp = sm + L_CTX + 8*kk - 256;
        FMA8(wv, xp, a0, a1, a2, a3)
      }
      #pragma unroll 4
      for (int kk = 0; kk < 32; kk++){
        uint4 wv = *(const uint4*)(P4 + (unsigned)kk*8192u + tid*8u);
        const float* xp = sm + L_H2 + 8*kk;
        FMA8(wv, xp, a0, a1, a2, a3)
      }
      sm[L_P4+tid] = (a0+a1)+(a2+a3);
    }
    __syncthreads();
    // 11. LSTM2 state update
    if (tid < 256){
      float gi=sm[L_P4+tid], gf=sm[L_P4+256+tid], gg=sm[L_P4+512+tid], go=sm[L_P4+768+tid];
      float c = sigm(gf)*sm[L_C2+tid] + sigm(gi)*tanhf(gg);
      sm[L_C2+tid] = c;
      sm[L_H2+tid] = sigm(go)*tanhf(c);
    }
    __syncthreads();
    // 12. acoustic projection: 4 threads / col over K=512 [h2,ctx]
    if (tid < 640){
      const int col = tid >> 2, qq = tid & 3;
      float a0 = 0.f, a1 = 0.f, a2 = 0.f, a3 = 0.f;
      #pragma unroll 4
      for (int kk = qq*16; kk < qq*16+16; kk++){
        uint4 wv = *(const uint4*)(P5 + (unsigned)kk*1280u + col*8u);
        const float* xp = (kk < 32) ? (sm + L_H2 + 8*kk) : (sm + L_CTX + 8*kk - 256);
        FMA8(wv, xp, a0, a1, a2, a3)
      }
      float acc = (a0+a1)+(a2+a3);
      acc += __shfl_xor(acc,1);
      acc += __shfl_xor(acc,2);
      if (qq==0){
        const int m = col >> 1, r = col & 1;
        out[(unsigned)b*NMELS*TMELS + m*TMELS + 2*t + r] = acc + acbv;
      }
    }
    __syncthreads();
  }
}

extern "C" void kernel_launch(void* const* d_in, const int* in_sizes, int n_in,
                              void* d_out, int out_size, void* d_ws, size_t ws_size,
                              hipStream_t stream) {
  (void)in_sizes; (void)n_in; (void)out_size; (void)ws_size;
  const float* mels   = (const float*)d_in[0];
  const float* memory = (const float*)d_in[1];
  const float* pre_W1 = (const float*)d_in[2];
  const float* pre_b1 = (const float*)d_in[3];
  const float* pre_W2 = (const float*)d_in[4];
  const float* pre_b2 = (const float*)d_in[5];
  const float* al_Wih = (const float*)d_in[6];
  const float* al_Whh = (const float*)d_in[7];
  const float* al_bih = (const float*)d_in[8];
  const float* al_bhh = (const float*)d_in[9];
  const float* att_W  = (const float*)d_in[10];
  const float* att_Wb = (const float*)d_in[11];
  const float* att_V  = (const float*)d_in[12];
  const float* att_F  = (const float*)d_in[13];
  const float* att_U  = (const float*)d_in[14];
  const float* att_T  = (const float*)d_in[15];
  const float* att_Tb = (const float*)d_in[16];
  const float* att_v  = (const float*)d_in[17];
  const float* prior  = (const float*)d_in[18];
  const float* dl_Wih = (const float*)d_in[19];
  const float* dl_Whh = (const float*)d_in[20];
  const float* dl_bih = (const float*)d_in[21];
  const float* dl_bhh = (const float*)d_in[22];
  const float* ac_W   = (const float*)d_in[23];
  const float* ac_b   = (const float*)d_in[24];
  float* ws  = (float*)d_ws;
  unsigned short* hw = (unsigned short*)d_ws;
  float* out = (float*)d_out;

  hipFuncSetAttribute((const void*)decoder, hipFuncAttributeMaxDynamicSharedMemorySize, DYNB);

  auto TR = [&](const float* src, unsigned off, int R, int C){
    int n = R*C;
    trk<<<dim3((n+255)/256), dim3(256), 0, stream>>>(src, ws + off, R, C);
  };
  auto PKH = [&](const float* src, unsigned off_us, int R, int C){
    int n = R*C;
    pk8h<<<dim3((n+255)/256), dim3(256), 0, stream>>>(src, hw + off_us, R, C);
  };
  PKH(al_Wih, HP1, 1024, 384);
  PKH(al_Whh, HP2, 1024, 256);
  PKH(dl_Wih, HP3, 1024, 512);
  PKH(dl_Whh, HP4, 1024, 256);
  PKH(ac_W,   HP5, 160, 512);
  TR(att_W,  WS_ATTWT, 128, 256);
  TR(pre_W1, WS_PW1T,  256, 80);
  TR(pre_W2, WS_PW2T,  128, 256);
  {
    int n = BB*TENC*MEM;
    pkmem<<<dim3((n+255)/256), dim3(256), 0, stream>>>(memory, (unsigned short*)(ws + WS_MEMH), n);
  }
  pkavt<<<dim3((128*168+255)/256), dim3(256), 0, stream>>>(att_V, (unsigned short*)(ws + WS_AVTH));

  prenetk<<<dim3(STEPS), dim3(256), 0, stream>>>(mels, pre_b1, pre_b2, ws);

  decoder<<<dim3(BB), dim3(BLK), DYNB, stream>>>(
      al_bih, al_bhh, dl_bih, dl_bhh, prior, att_F,
      att_Wb, att_U, att_T, att_Tb, att_v,
      ac_b, ws, out);
}

// Round 21
// 25998.651 us; speedup vs baseline: 1.5337x; 1.1491x over previous
//
#include <hip/hip_runtime.h>
#include <math.h>

#define BB 32
#define TENC 200
#define NMELS 80
#define TMELS 400
#define STEPS 200
#define MEM 256
#define PRE1N 256
#define PRE2N 128
#define AD 128
#define DK 21
#define DF 8
#define SK 21
#define SF 8
#define PL 11
#define BLK 1024

// ushort offsets (kk-major quarter packs):
#define QW1 0u         // LSTM1 [4][20][1024][8] bf16 (K=640: ctx|pre|h1), 655360 ushorts
#define QW2 655360u    // LSTM2 [4][24][1024][8] bf16 (K=768: h1|ctx|h2), ends 1441792
#define HP5 1441792u   // ac_W [64][160][8] bf16 (K=512), ends 1523712
// float offsets:
#define WS_ATTWT 761856u   // att_W^T fp32 [256][128] (staged to LDS bf16 once)
#define WS_PW1T  816128u   // pre_W1^T [80][256]
#define WS_PW2T  836608u   // pre_W2^T [256][128]
#define WS_PRE2  869376u   // prenet out [200][32][128] fp32, end 1688576
#define WS_MEMH  1688576u  // memory bf16 [32][200][256] ushorts, end 2507776
#define WS_AVTH  2507776u  // att_V^T bf16 [128][168] ushorts, end 2518528

// dynamic-LDS float offsets
#define L_XS   0      // 768: activation concat (step1: [ctx|pre|h1]; step9b: [h1|ctx|h2])
#define L_H1   768
#define L_C1   1024
#define L_H2   1280
#define L_C2   1536
#define L_CTX  1792
#define L_AL   2048   // 200
#define L_PS   2248   // 200
#define L_ES   2448   // 200
#define L_P4   2656   // 4096: k-split partials / q-partials / ctx partials (time-aliased)
#define L_QS   6752   // 128
#define L_GS   6880   // 168
#define L_FS   7048   // 1600
#define L_WF   8648   // 168
#define L_PR   8816   // 11
#define L_RB   8828   // 17
#define L_B1   8848   // 1024
#define L_B2   9872   // 1024
#define L_AW   10896  // att_W^T bf16: 32768 ushorts = 16384 floats
#define DYNF   27280
#define DYNB   (DYNF*4)

__device__ __forceinline__ float sigm(float x){ return 1.f/(1.f+expf(-x)); }
__device__ __forceinline__ float tanh_fast(float x){
  float ax = fabsf(x);
  float z = __expf(-2.f*ax);
  float r = (1.f - z)/(1.f + z);
  return (x < 0.f) ? -r : r;
}
__device__ __forceinline__ unsigned short to_bf16(float f){
  unsigned u = __float_as_uint(f);
  return (unsigned short)((u + 0x7fffu + ((u>>16)&1u)) >> 16);
}

// 8 bf16 weights (uint4) FMA'd against two float4 activations into one acc
#define FMA8S(wv, xa, xb, acc) \
  acc += __uint_as_float((wv).x<<16)*(xa).x + __uint_as_float((wv).x&0xffff0000u)*(xa).y \
       + __uint_as_float((wv).y<<16)*(xa).z + __uint_as_float((wv).y&0xffff0000u)*(xa).w \
       + __uint_as_float((wv).z<<16)*(xb).x + __uint_as_float((wv).z&0xffff0000u)*(xb).y \
       + __uint_as_float((wv).w<<16)*(xb).z + __uint_as_float((wv).w&0xffff0000u)*(xb).w;
// pointer-form for phase 12
#define FMA8(wv, xp, a0, a1, a2, a3) \
  a0 += __uint_as_float((wv).x << 16)*(xp)[0] + __uint_as_float((wv).x & 0xffff0000u)*(xp)[1]; \
  a1 += __uint_as_float((wv).y << 16)*(xp)[2] + __uint_as_float((wv).y & 0xffff0000u)*(xp)[3]; \
  a2 += __uint_as_float((wv).z << 16)*(xp)[4] + __uint_as_float((wv).z & 0xffff0000u)*(xp)[5]; \
  a3 += __uint_as_float((wv).w << 16)*(xp)[6] + __uint_as_float((wv).w & 0xffff0000u)*(xp)[7];

// transpose: src[R][C] -> dst[C][R]
__global__ __launch_bounds__(256) void trk(const float* __restrict__ s, float* __restrict__ d, int R, int C){
  int i = blockIdx.x*256 + threadIdx.x;
  if (i < R*C){ int r = i / C, c = i - r*C; d[c*R + r] = s[i]; }
}
// LSTM1 kk-major quarter pack: k=640, quarter 160 => [q][kk<20][c<1024][e<8]
__global__ __launch_bounds__(256) void pkq1c(const float* __restrict__ wih, const float* __restrict__ whh,
                                             unsigned short* __restrict__ d){
  int i = blockIdx.x*256 + threadIdx.x;
  if (i < 1024*640){
    int c = i / 640, k = i - c*640;
    float v = (k < 384) ? wih[c*384 + k] : whh[c*256 + (k-384)];
    int q = k / 160, kr = k - 160*q, kk = kr >> 3, e = kr & 7;
    d[((unsigned)((q*20 + kk)*1024 + c))*8u + e] = to_bf16(v);
  }
}
// LSTM2 kk-major quarter pack: k=768, quarter 192 => [q][kk<24][c<1024][e<8]
__global__ __launch_bounds__(256) void pkq2c(const float* __restrict__ wih, const float* __restrict__ whh,
                                             unsigned short* __restrict__ d){
  int i = blockIdx.x*256 + threadIdx.x;
  if (i < 1024*768){
    int c = i / 768, k = i - c*768;
    float v = (k < 512) ? wih[c*512 + k] : whh[c*256 + (k-512)];
    int q = k / 192, kr = k - 192*q, kk = kr >> 3, e = kr & 7;
    d[((unsigned)((q*24 + kk)*1024 + c))*8u + e] = to_bf16(v);
  }
}
// 8-wide bf16 pack (ac_W): src[R][C] -> dst[(c>>3)*R*8 + r*8 + (c&7)]
__global__ __launch_bounds__(256) void pk8h(const float* __restrict__ s, unsigned short* __restrict__ d, int R, int C){
  int i = blockIdx.x*256 + threadIdx.x;
  if (i < R*C){ int r = i / C, c = i - r*C; d[(unsigned)(c>>3)*(unsigned)R*8u + (unsigned)r*8u + (c&7)] = to_bf16(s[i]); }
}
__global__ __launch_bounds__(256) void pkmem(const float* __restrict__ s, unsigned short* __restrict__ d, int n){
  int i = blockIdx.x*256 + threadIdx.x;
  if (i < n) d[i] = to_bf16(s[i]);
}
__global__ __launch_bounds__(256) void pkavt(const float* __restrict__ s, unsigned short* __restrict__ d){
  int i = blockIdx.x*256 + threadIdx.x;
  if (i < 128*168){ int k = i/168, a = i - k*168; d[i] = to_bf16(s[a*128 + k]); }
}

// prenet for all 200 steps (proven)
__global__ __launch_bounds__(256) void prenetk(const float* __restrict__ mels,
    const float* __restrict__ b1, const float* __restrict__ b2, float* __restrict__ ws){
  int t = blockIdx.x, tid = threadIdx.x;
  __shared__ float xS[BB*NMELS];
  __shared__ float p1S[BB*PRE1N];
  const float* W1T = ws + WS_PW1T;
  const float* W2T = ws + WS_PW2T;
  for (int i=tid;i<BB*NMELS;i+=256){
    int r = i/NMELS, k = i - r*NMELS;
    xS[i] = (t==0)?0.f : mels[r*NMELS*TMELS + k*TMELS + (2*t-1)];
  }
  __syncthreads();
  {
    float acc[BB];
    #pragma unroll
    for (int r=0;r<BB;r++) acc[r]=0.f;
    for (int k=0;k<NMELS;k++){
      float w = W1T[k*PRE1N + tid];
      #pragma unroll
      for (int r=0;r<BB;r++) acc[r] += xS[r*NMELS+k]*w;
    }
    float bb = b1[tid];
    #pragma unroll
    for (int r=0;r<BB;r++) p1S[r*PRE1N+tid] = fmaxf(acc[r]+bb, 0.f);
  }
  __syncthreads();
  if (tid < PRE2N){
    float acc[BB];
    #pragma unroll
    for (int r=0;r<BB;r++) acc[r]=0.f;
    for (int k=0;k<PRE1N;k++){
      float w = W2T[k*PRE2N + tid];
      #pragma unroll
      for (int r=0;r<BB;r++) acc[r] += p1S[r*PRE1N+k]*w;
    }
    float bb = b2[tid];
    #pragma unroll
    for (int r=0;r<BB;r++) ws[WS_PRE2 + ((unsigned)t*BB + r)*PRE2N + tid] = fmaxf(acc[r]+bb, 0.f);
  }
}

// ONE BLOCK PER BATCH. k-split x4 GEMVs w/ coalesced kk-major packs; attW^T bf16 LDS;
// bf16 memory/attV^T; scalar-cache uniforms.
__global__ __launch_bounds__(BLK) void decoder(
    const float* __restrict__ albih, const float* __restrict__ albhh,
    const float* __restrict__ dlbih, const float* __restrict__ dlbhh,
    const float* __restrict__ prior, const float* __restrict__ attF,
    const float* __restrict__ attWb, const float* __restrict__ attU,
    const float* __restrict__ attT, const float* __restrict__ attTb,
    const float* __restrict__ attv,
    const float* __restrict__ acb, const float* __restrict__ ws,
    float* __restrict__ out){
  extern __shared__ float sm[];
  const int b = blockIdx.x, tid = threadIdx.x;
  unsigned short* aWh = (unsigned short*)(sm + L_AW);
  const unsigned* aWu = (const unsigned*)(sm + L_AW);

  // ---- one-time init ----
  if (tid < 256){ sm[L_H1+tid]=0.f; sm[L_C1+tid]=0.f; sm[L_H2+tid]=0.f; sm[L_C2+tid]=0.f; sm[L_CTX+tid]=0.f; }
  if (tid < TENC) sm[L_AL+tid] = (tid==0)?1.f:0.f;
  sm[L_B1+tid] = albih[tid] + albhh[tid];
  sm[L_B2+tid] = dlbih[tid] + dlbhh[tid];
  if (tid < SF*SK) sm[L_WF+tid] = attF[tid];
  if (tid < PL)    sm[L_PR+tid] = prior[tid];
  for (int i = tid; i < 32768; i += BLK) aWh[i] = to_bf16(ws[WS_ATTWT + i]);
  __syncthreads();

  const unsigned short* hw = (const unsigned short*)ws;
  const unsigned short* Q1 = hw + QW1;
  const unsigned short* Q2 = hw + QW2;
  const unsigned short* P5 = hw + HP5;
  const unsigned* memh = (const unsigned*)(ws + WS_MEMH);
  const unsigned short* avth = (const unsigned short*)(ws + WS_AVTH);
  const float acbv  = (tid < 640) ? acb[tid >> 2] : 0.f;
  const int q = tid >> 8, c0 = tid & 255;

  for (int t = 0; t < STEPS; ++t){
    // 1. xS = [ctx 256 | pre 128 | h1 256]
    if (tid < 256) sm[L_XS+tid] = sm[L_CTX+tid];
    else if (tid < 384) sm[L_XS+tid] = __builtin_nontemporal_load(&ws[WS_PRE2 + ((unsigned)t*BB + b)*PRE2N + (tid-256)]);
    else if (tid < 640) sm[L_XS+tid] = sm[L_H1 + (tid-384)];
    __syncthreads();
    // 2. LSTM1 partials: quarter q (160 k), cols c0+256j — coalesced kk-major loads
    {
      const float* xq = sm + L_XS + 160*q;
      const unsigned short* Wq = Q1 + (unsigned)q*163840u;
      float a0=0.f, a1=0.f, a2=0.f, a3=0.f;
      #pragma unroll 4
      for (int kk = 0; kk < 20; kk++){
        float4 xa = *(const float4*)(xq + 8*kk);
        float4 xb = *(const float4*)(xq + 8*kk + 4);
        const unsigned short* wr = Wq + (unsigned)kk*8192u + c0*8u;
        uint4 w0 = *(const uint4*)(wr);
        uint4 w1 = *(const uint4*)(wr + 2048);
        uint4 w2 = *(const uint4*)(wr + 4096);
        uint4 w3 = *(const uint4*)(wr + 6144);
        FMA8S(w0, xa, xb, a0)
        FMA8S(w1, xa, xb, a1)
        FMA8S(w2, xa, xb, a2)
        FMA8S(w3, xa, xb, a3)
      }
      sm[L_P4 + q*1024 + c0      ] = a0;
      sm[L_P4 + q*1024 + c0 + 256] = a1;
      sm[L_P4 + q*1024 + c0 + 512] = a2;
      sm[L_P4 + q*1024 + c0 + 768] = a3;
    }
    __syncthreads();
    // 3. LSTM1 gates + state update
    if (tid < 256){
      float g[4];
      #pragma unroll
      for (int gg2 = 0; gg2 < 4; gg2++){
        int col = gg2*256 + tid;
        g[gg2] = sm[L_B1+col] + sm[L_P4+col] + sm[L_P4+1024+col] + sm[L_P4+2048+col] + sm[L_P4+3072+col];
      }
      float c = sigm(g[1])*sm[L_C1+tid] + sigm(g[0])*tanhf(g[2]);
      sm[L_C1+tid] = c;
      sm[L_H1+tid] = sigm(g[3])*tanhf(c);
    }
    __syncthreads();
    // 4. q-partials (tid<512, attW^T bf16 in LDS) || prior+static convs (tid in [512,712))
    if (tid < 512){
      const int quarter = tid >> 7, a = tid & 127;
      const int sel = a & 1, au = a >> 1;
      float s = 0.f;
      for (int k = 64*quarter; k < 64*quarter+64; k++){
        unsigned u = aWu[k*64 + au];
        float wv = __uint_as_float(sel ? (u & 0xffff0000u) : (u << 16));
        s += sm[L_H1+k]*wv;
      }
      sm[L_P4 + tid] = s;
    } else if (tid < 512+TENC){
      const int pos = tid - 512;
      float s = 0.f;
      #pragma unroll
      for (int jj = 0; jj < PL; jj++){ int qq = pos - jj; if (qq >= 0) s += sm[L_PR+jj]*sm[L_AL+qq]; }
      sm[L_PS+pos] = logf(fmaxf(s, 1e-6f));
      #pragma unroll
      for (int c = 0; c < SF; c++){
        float s2 = 0.f;
        #pragma unroll
        for (int k = 0; k < SK; k++){ int qq = pos + k - 10; if (qq>=0 && qq<TENC) s2 += sm[L_WF+c*SK+k]*sm[L_AL+qq]; }
        sm[L_FS + c*TENC + pos] = s2;
      }
    }
    __syncthreads();
    // 5. q = tanh
    if (tid < AD) sm[L_QS+tid] = tanhf(attWb[tid] + sm[L_P4+tid] + sm[L_P4+128+tid] + sm[L_P4+256+tid] + sm[L_P4+384+tid]);
    __syncthreads();
    // 6. G = attV @ q (attV^T bf16)
    if (tid < DF*DK){
      float a = 0.f;
      for (int k = 0; k < AD; k++) a += sm[L_QS+k]*__uint_as_float(((unsigned)avth[k*(DF*DK)+tid])<<16);
      sm[L_GS+tid] = a;
    }
    __syncthreads();
    // 7. e[pos] (4 threads/pos)
    if (tid < 4*TENC){
      const int pos = tid >> 2, qr = tid & 3;
      float g[DF];
      #pragma unroll
      for (int c=0;c<DF;c++){
        float s=0.f;
        #pragma unroll
        for (int k=0;k<DK;k++){
          int q2 = pos + k - 10;
          if (q2>=0 && q2<TENC) s += sm[L_AL+q2]*sm[L_GS+c*DK+k];
        }
        g[c]=s;
      }
      float fv[SF];
      #pragma unroll
      for (int s2=0;s2<SF;s2++) fv[s2] = sm[L_FS + s2*TENC + pos];
      float pp = 0.f;
      for (int h = qr*32; h < qr*32+32; h++){
        float u = attTb[h];
        #pragma unroll
        for (int s2=0;s2<SF;s2++) u += attU[h*SF+s2]*fv[s2];
        #pragma unroll
        for (int c=0;c<DF;c++) u += attT[h*DF+c]*g[c];
        pp += attv[h]*tanh_fast(u);
      }
      pp += __shfl_xor(pp,1);
      pp += __shfl_xor(pp,2);
      if (qr==0) sm[L_ES+pos] = pp + sm[L_PS+pos];
    }
    __syncthreads();
    // 8. softmax over 200
    float ex;
    {
      float v = (tid<TENC)? sm[L_ES+tid] : -3.0e38f;
      for (int o=1;o<64;o<<=1) v = fmaxf(v, __shfl_xor(v,o));
      if ((tid&63)==0) sm[L_RB+(tid>>6)] = v;
      __syncthreads();
      if (tid==0){ sm[L_RB+16] = fmaxf(fmaxf(sm[L_RB],sm[L_RB+1]), fmaxf(sm[L_RB+2],sm[L_RB+3])); }
      __syncthreads();
      float m = sm[L_RB+16];
      ex = (tid<TENC)? expf(sm[L_ES+tid]-m) : 0.f;
      float sv = ex;
      for (int o=1;o<64;o<<=1) sv += __shfl_xor(sv,o);
      __syncthreads();
      if ((tid&63)==0) sm[L_RB+(tid>>6)] = sv;
      __syncthreads();
      if (tid==0){ sm[L_RB+16] = 1.f/(sm[L_RB]+sm[L_RB+1]+sm[L_RB+2]+sm[L_RB+3]); }
      __syncthreads();
      float inv = sm[L_RB+16];
      if (tid<TENC){
        float a = ex*inv;
        sm[L_AL+tid] = a;
        out[1024000 + b*TENC*STEPS + tid*STEPS + t] = a;
      }
    }
    __syncthreads();
    // 9. ctx partials: bf16 memory, cached
    {
      const int grp2 = tid >> 7, jp = tid & 127;
      const unsigned base = ((unsigned)b*TENC)*128u + jp;
      float a0 = 0.f, a1 = 0.f;
      for (int p = grp2*25; p < grp2*25+25; p++){
        unsigned u = memh[base + (unsigned)p*128u];
        float al = sm[L_AL+p];
        a0 += al*__uint_as_float(u << 16);
        a1 += al*__uint_as_float(u & 0xffff0000u);
      }
      sm[L_P4 + grp2*256 + 2*jp    ] = a0;
      sm[L_P4 + grp2*256 + 2*jp + 1] = a1;
    }
    __syncthreads();
    // 9b. ctx reduce + build xS2 = [h1 | ctx | h2]
    if (tid < 256){
      float c = 0.f;
      #pragma unroll
      for (int g2 = 0; g2 < 8; g2++) c += sm[L_P4 + g2*256 + tid];
      sm[L_CTX+tid] = c;
      sm[L_XS+256+tid] = c;
    } else if (tid < 512){
      sm[L_XS + (tid-256)] = sm[L_H1 + (tid-256)];
    } else if (tid < 768){
      sm[L_XS + tid] = sm[L_H2 + (tid-512)];
    }
    __syncthreads();
    // 10. LSTM2 partials: quarter q (192 k), cols c0+256j — coalesced kk-major loads
    {
      const float* xq = sm + L_XS + 192*q;
      const unsigned short* Wq = Q2 + (unsigned)q*196608u;
      float a0=0.f, a1=0.f, a2=0.f, a3=0.f;
      #pragma unroll 4
      for (int kk = 0; kk < 24; kk++){
        float4 xa = *(const float4*)(xq + 8*kk);
        float4 xb = *(const float4*)(xq + 8*kk + 4);
        const unsigned short* wr = Wq + (unsigned)kk*8192u + c0*8u;
        uint4 w0 = *(const uint4*)(wr);
        uint4 w1 = *(const uint4*)(wr + 2048);
        uint4 w2 = *(const uint4*)(wr + 4096);
        uint4 w3 = *(const uint4*)(wr + 6144);
        FMA8S(w0, xa, xb, a0)
        FMA8S(w1, xa, xb, a1)
        FMA8S(w2, xa, xb, a2)
        FMA8S(w3, xa, xb, a3)
      }
      sm[L_P4 + q*1024 + c0      ] = a0;
      sm[L_P4 + q*1024 + c0 + 256] = a1;
      sm[L_P4 + q*1024 + c0 + 512] = a2;
      sm[L_P4 + q*1024 + c0 + 768] = a3;
    }
    __syncthreads();
    // 11. LSTM2 gates + state update
    if (tid < 256){
      float g[4];
      #pragma unroll
      for (int gg2 = 0; gg2 < 4; gg2++){
        int col = gg2*256 + tid;
        g[gg2] = sm[L_B2+col] + sm[L_P4+col] + sm[L_P4+1024+col] + sm[L_P4+2048+col] + sm[L_P4+3072+col];
      }
      float c = sigm(g[1])*sm[L_C2+tid] + sigm(g[0])*tanhf(g[2]);
      sm[L_C2+tid] = c;
      sm[L_H2+tid] = sigm(g[3])*tanhf(c);
    }
    __syncthreads();
    // 12. acoustic projection: 4 threads / col over K=512 [h2,ctx]
    if (tid < 640){
      const int col = tid >> 2, qq = tid & 3;
      float a0 = 0.f, a1 = 0.f, a2 = 0.f, a3 = 0.f;
      #pragma unroll 4
      for (int kk = qq*16; kk < qq*16+16; kk++){
        uint4 wv = *(const uint4*)(P5 + (unsigned)kk*1280u + col*8u);
        const float* xp = (kk < 32) ? (sm + L_H2 + 8*kk) : (sm + L_CTX + 8*kk - 256);
        FMA8(wv, xp, a0, a1, a2, a3)
      }
      float acc = (a0+a1)+(a2+a3);
      acc += __shfl_xor(acc,1);
      acc += __shfl_xor(acc,2);
      if (qq==0){
        const int m = col >> 1, r = col & 1;
        out[(unsigned)b*NMELS*TMELS + m*TMELS + 2*t + r] = acc + acbv;
      }
    }
    __syncthreads();
  }
}

extern "C" void kernel_launch(void* const* d_in, const int* in_sizes, int n_in,
                              void* d_out, int out_size, void* d_ws, size_t ws_size,
                              hipStream_t stream) {
  (void)in_sizes; (void)n_in; (void)out_size; (void)ws_size;
  const float* mels   = (const float*)d_in[0];
  const float* memory = (const float*)d_in[1];
  const float* pre_W1 = (const float*)d_in[2];
  const float* pre_b1 = (const float*)d_in[3];
  const float* pre_W2 = (const float*)d_in[4];
  const float* pre_b2 = (const float*)d_in[5];
  const float* al_Wih = (const float*)d_in[6];
  const float* al_Whh = (const float*)d_in[7];
  const float* al_bih = (const float*)d_in[8];
  const float* al_bhh = (const float*)d_in[9];
  const float* att_W  = (const float*)d_in[10];
  const float* att_Wb = (const float*)d_in[11];
  const float* att_V  = (const float*)d_in[12];
  const float* att_F  = (const float*)d_in[13];
  const float* att_U  = (const float*)d_in[14];
  const float* att_T  = (const float*)d_in[15];
  const float* att_Tb = (const float*)d_in[16];
  const float* att_v  = (const float*)d_in[17];
  const float* prior  = (const float*)d_in[18];
  const float* dl_Wih = (const float*)d_in[19];
  const float* dl_Whh = (const float*)d_in[20];
  const float* dl_bih = (const float*)d_in[21];
  const float* dl_bhh = (const float*)d_in[22];
  const float* ac_W   = (const float*)d_in[23];
  const float* ac_b   = (const float*)d_in[24];
  float* ws  = (float*)d_ws;
  unsigned short* hw = (unsigned short*)d_ws;
  float* out = (float*)d_out;

  hipFuncSetAttribute((const void*)decoder, hipFuncAttributeMaxDynamicSharedMemorySize, DYNB);

  auto TR = [&](const float* src, unsigned off, int R, int C){
    int n = R*C;
    trk<<<dim3((n+255)/256), dim3(256), 0, stream>>>(src, ws + off, R, C);
  };
  pkq1c<<<dim3((1024*640+255)/256), dim3(256), 0, stream>>>(al_Wih, al_Whh, hw + QW1);
  pkq2c<<<dim3((1024*768+255)/256), dim3(256), 0, stream>>>(dl_Wih, dl_Whh, hw + QW2);
  pk8h<<<dim3((160*512+255)/256), dim3(256), 0, stream>>>(ac_W, hw + HP5, 160, 512);
  TR(att_W,  WS_ATTWT, 128, 256);
  TR(pre_W1, WS_PW1T,  256, 80);
  TR(pre_W2, WS_PW2T,  128, 256);
  {
    int n = BB*TENC*MEM;
    pkmem<<<dim3((n+255)/256), dim3(256), 0, stream>>>(memory, (unsigned short*)(ws + WS_MEMH), n);
  }
  pkavt<<<dim3((128*168+255)/256), dim3(256), 0, stream>>>(att_V, (unsigned short*)(ws + WS_AVTH));

  prenetk<<<dim3(STEPS), dim3(256), 0, stream>>>(mels, pre_b1, pre_b2, ws);

  decoder<<<dim3(BB), dim3(BLK), DYNB, stream>>>(
      al_bih, al_bhh, dl_bih, dl_bhh, prior, att_F,
      att_Wb, att_U, att_T, att_Tb, att_v,
      ac_b, ws, out);
}

// Round 22
// 23410.909 us; speedup vs baseline: 1.7033x; 1.1105x over previous
//
#include <hip/hip_runtime.h>
#include <math.h>

#define BB 32
#define TENC 200
#define NMELS 80
#define TMELS 400
#define STEPS 200
#define MEM 256
#define PRE1N 256
#define PRE2N 128
#define AD 128
#define DK 21
#define DF 8
#define SK 21
#define SF 8
#define PL 11
#define BLK 1024

// ushort offsets (kk-major quarter packs):
#define QW1 0u         // LSTM1 [4][20][1024][8] bf16 (K=640: ctx|pre|h1)
#define QW2 655360u    // LSTM2 [4][24][1024][8] bf16 (K=768: h1|ctx|h2)
#define HP5 1441792u   // ac_W [64][160][8] bf16 (K=512), ends 1523712
// float offsets:
#define WS_ATTWT 761856u
#define WS_PW1T  816128u
#define WS_PW2T  836608u
#define WS_PRE2  869376u   // [200][32][128] fp32
#define WS_MEMH  1688576u  // memory bf16
#define WS_AVTH  2507776u  // att_V^T bf16

// dynamic-LDS float offsets
#define L_XS   0      // 768 activation concat
#define L_H1   768
#define L_C1   1024
#define L_H2   1280
#define L_C2   1536
#define L_CTX  1792
#define L_AL   2048
#define L_PS   2248
#define L_ES   2448
#define L_P4   2656   // 4096 partials
#define L_QS   6752
#define L_GS   6880
#define L_FS   7048
#define L_WF   8648
#define L_PR   8816
#define L_RB   8828
#define L_B1   8848
#define L_B2   9872
#define L_AW   10896  // att_W^T bf16 (16384 floats)
#define DYNF   27280
#define DYNB   (DYNF*4)

__device__ __forceinline__ float sigm(float x){ return 1.f/(1.f+expf(-x)); }
__device__ __forceinline__ float tanh_fast(float x){
  float ax = fabsf(x);
  float z = __expf(-2.f*ax);
  float r = (1.f - z)/(1.f + z);
  return (x < 0.f) ? -r : r;
}
__device__ __forceinline__ unsigned short to_bf16(float f){
  unsigned u = __float_as_uint(f);
  return (unsigned short)((u + 0x7fffu + ((u>>16)&1u)) >> 16);
}

#define FMA8S(wv, xa, xb, acc) \
  acc += __uint_as_float((wv).x<<16)*(xa).x + __uint_as_float((wv).x&0xffff0000u)*(xa).y \
       + __uint_as_float((wv).y<<16)*(xa).z + __uint_as_float((wv).y&0xffff0000u)*(xa).w \
       + __uint_as_float((wv).z<<16)*(xb).x + __uint_as_float((wv).z&0xffff0000u)*(xb).y \
       + __uint_as_float((wv).w<<16)*(xb).z + __uint_as_float((wv).w&0xffff0000u)*(xb).w;

// transpose
__global__ __launch_bounds__(256) void trk(const float* __restrict__ s, float* __restrict__ d, int R, int C){
  int i = blockIdx.x*256 + threadIdx.x;
  if (i < R*C){ int r = i / C, c = i - r*C; d[c*R + r] = s[i]; }
}
__global__ __launch_bounds__(256) void pkq1c(const float* __restrict__ wih, const float* __restrict__ whh,
                                             unsigned short* __restrict__ d){
  int i = blockIdx.x*256 + threadIdx.x;
  if (i < 1024*640){
    int c = i / 640, k = i - c*640;
    float v = (k < 384) ? wih[c*384 + k] : whh[c*256 + (k-384)];
    int q = k / 160, kr = k - 160*q, kk = kr >> 3, e = kr & 7;
    d[((unsigned)((q*20 + kk)*1024 + c))*8u + e] = to_bf16(v);
  }
}
__global__ __launch_bounds__(256) void pkq2c(const float* __restrict__ wih, const float* __restrict__ whh,
                                             unsigned short* __restrict__ d){
  int i = blockIdx.x*256 + threadIdx.x;
  if (i < 1024*768){
    int c = i / 768, k = i - c*768;
    float v = (k < 512) ? wih[c*512 + k] : whh[c*256 + (k-512)];
    int q = k / 192, kr = k - 192*q, kk = kr >> 3, e = kr & 7;
    d[((unsigned)((q*24 + kk)*1024 + c))*8u + e] = to_bf16(v);
  }
}
__global__ __launch_bounds__(256) void pk8h(const float* __restrict__ s, unsigned short* __restrict__ d, int R, int C){
  int i = blockIdx.x*256 + threadIdx.x;
  if (i < R*C){ int r = i / C, c = i - r*C; d[(unsigned)(c>>3)*(unsigned)R*8u + (unsigned)r*8u + (c&7)] = to_bf16(s[i]); }
}
__global__ __launch_bounds__(256) void pkmem(const float* __restrict__ s, unsigned short* __restrict__ d, int n){
  int i = blockIdx.x*256 + threadIdx.x;
  if (i < n) d[i] = to_bf16(s[i]);
}
__global__ __launch_bounds__(256) void pkavt(const float* __restrict__ s, unsigned short* __restrict__ d){
  int i = blockIdx.x*256 + threadIdx.x;
  if (i < 128*168){ int k = i/168, a = i - k*168; d[i] = to_bf16(s[a*128 + k]); }
}

// prenet (proven)
__global__ __launch_bounds__(256) void prenetk(const float* __restrict__ mels,
    const float* __restrict__ b1, const float* __restrict__ b2, float* __restrict__ ws){
  int t = blockIdx.x, tid = threadIdx.x;
  __shared__ float xS[BB*NMELS];
  __shared__ float p1S[BB*PRE1N];
  const float* W1T = ws + WS_PW1T;
  const float* W2T = ws + WS_PW2T;
  for (int i=tid;i<BB*NMELS;i+=256){
    int r = i/NMELS, k = i - r*NMELS;
    xS[i] = (t==0)?0.f : mels[r*NMELS*TMELS + k*TMELS + (2*t-1)];
  }
  __syncthreads();
  {
    float acc[BB];
    #pragma unroll
    for (int r=0;r<BB;r++) acc[r]=0.f;
    for (int k=0;k<NMELS;k++){
      float w = W1T[k*PRE1N + tid];
      #pragma unroll
      for (int r=0;r<BB;r++) acc[r] += xS[r*NMELS+k]*w;
    }
    float bb = b1[tid];
    #pragma unroll
    for (int r=0;r<BB;r++) p1S[r*PRE1N+tid] = fmaxf(acc[r]+bb, 0.f);
  }
  __syncthreads();
  if (tid < PRE2N){
    float acc[BB];
    #pragma unroll
    for (int r=0;r<BB;r++) acc[r]=0.f;
    for (int k=0;k<PRE1N;k++){
      float w = W2T[k*PRE2N + tid];
      #pragma unroll
      for (int r=0;r<BB;r++) acc[r] += p1S[r*PRE1N+k]*w;
    }
    float bb = b2[tid];
    #pragma unroll
    for (int r=0;r<BB;r++) ws[WS_PRE2 + ((unsigned)t*BB + r)*PRE2N + tid] = fmaxf(acc[r]+bb, 0.f);
  }
}

// ONE BLOCK PER BATCH. 11 barriers/step: proj folded into phase 4, xS1 built in phase 11,
// single-wave softmax.
__global__ __launch_bounds__(BLK) void decoder(
    const float* __restrict__ albih, const float* __restrict__ albhh,
    const float* __restrict__ dlbih, const float* __restrict__ dlbhh,
    const float* __restrict__ prior, const float* __restrict__ attF,
    const float* __restrict__ attWb, const float* __restrict__ attU,
    const float* __restrict__ attT, const float* __restrict__ attTb,
    const float* __restrict__ attv,
    const float* __restrict__ acb, const float* __restrict__ ws,
    float* __restrict__ out){
  extern __shared__ float sm[];
  const int b = blockIdx.x, tid = threadIdx.x;
  unsigned short* aWh = (unsigned short*)(sm + L_AW);
  const unsigned* aWu = (const unsigned*)(sm + L_AW);

  // ---- one-time init (also builds xS1 for t=0) ----
  if (tid < 256){
    sm[L_H1+tid]=0.f; sm[L_C1+tid]=0.f; sm[L_H2+tid]=0.f; sm[L_C2+tid]=0.f; sm[L_CTX+tid]=0.f;
    sm[L_XS+tid]=0.f;            // ctx part of xS1(0)
    sm[L_XS+384+tid]=0.f;        // h1 part (covers 384..640)
  }
  if (tid >= 256 && tid < 384) sm[L_XS+tid] = ws[WS_PRE2 + ((unsigned)0*BB + b)*PRE2N + (tid-256)];
  if (tid < TENC) sm[L_AL+tid] = (tid==0)?1.f:0.f;
  sm[L_B1+tid] = albih[tid] + albhh[tid];
  sm[L_B2+tid] = dlbih[tid] + dlbhh[tid];
  if (tid < SF*SK) sm[L_WF+tid] = attF[tid];
  if (tid < PL)    sm[L_PR+tid] = prior[tid];
  for (int i = tid; i < 32768; i += BLK) aWh[i] = to_bf16(ws[WS_ATTWT + i]);
  __syncthreads();

  const unsigned short* hw = (const unsigned short*)ws;
  const unsigned short* Q1 = hw + QW1;
  const unsigned short* Q2 = hw + QW2;
  const unsigned short* P5 = hw + HP5;
  const unsigned* memh = (const unsigned*)(ws + WS_MEMH);
  const unsigned short* avth = (const unsigned short*)(ws + WS_AVTH);
  const int q = tid >> 8, c0 = tid & 255;

  for (int t = 0; t < STEPS; ++t){
    // 2. LSTM1 partials (xS1 built by prev phase 11 / prologue)
    {
      const float* xq = sm + L_XS + 160*q;
      const unsigned short* Wq = Q1 + (unsigned)q*163840u;
      float a0=0.f, a1=0.f, a2=0.f, a3=0.f;
      #pragma unroll 4
      for (int kk = 0; kk < 20; kk++){
        float4 xa = *(const float4*)(xq + 8*kk);
        float4 xb = *(const float4*)(xq + 8*kk + 4);
        const unsigned short* wr = Wq + (unsigned)kk*8192u + c0*8u;
        uint4 w0 = *(const uint4*)(wr);
        uint4 w1 = *(const uint4*)(wr + 2048);
        uint4 w2 = *(const uint4*)(wr + 4096);
        uint4 w3 = *(const uint4*)(wr + 6144);
        FMA8S(w0, xa, xb, a0)
        FMA8S(w1, xa, xb, a1)
        FMA8S(w2, xa, xb, a2)
        FMA8S(w3, xa, xb, a3)
      }
      sm[L_P4 + q*1024 + c0      ] = a0;
      sm[L_P4 + q*1024 + c0 + 256] = a1;
      sm[L_P4 + q*1024 + c0 + 512] = a2;
      sm[L_P4 + q*1024 + c0 + 768] = a3;
    }
    __syncthreads();
    // 3. LSTM1 gates + state update
    if (tid < 256){
      float g[4];
      #pragma unroll
      for (int gg2 = 0; gg2 < 4; gg2++){
        int col = gg2*256 + tid;
        g[gg2] = sm[L_B1+col] + sm[L_P4+col] + sm[L_P4+1024+col] + sm[L_P4+2048+col] + sm[L_P4+3072+col];
      }
      float c = sigm(g[1])*sm[L_C1+tid] + sigm(g[0])*tanhf(g[2]);
      sm[L_C1+tid] = c;
      sm[L_H1+tid] = sigm(g[3])*tanhf(c);
    }
    __syncthreads();
    // 4. q-partials (tid<512) || convs (512..711) || proj(t-1) (712..871)
    if (tid < 512){
      const int quarter = tid >> 7, a = tid & 127;
      const int sel = a & 1, au = a >> 1;
      float s = 0.f;
      for (int k = 64*quarter; k < 64*quarter+64; k++){
        unsigned u = aWu[k*64 + au];
        float wv = __uint_as_float(sel ? (u & 0xffff0000u) : (u << 16));
        s += sm[L_H1+k]*wv;
      }
      sm[L_P4 + tid] = s;
    } else if (tid < 512+TENC){
      const int pos = tid - 512;
      float s = 0.f;
      #pragma unroll
      for (int jj = 0; jj < PL; jj++){ int qq = pos - jj; if (qq >= 0) s += sm[L_PR+jj]*sm[L_AL+qq]; }
      sm[L_PS+pos] = logf(fmaxf(s, 1e-6f));
      #pragma unroll
      for (int c = 0; c < SF; c++){
        float s2 = 0.f;
        #pragma unroll
        for (int k = 0; k < SK; k++){ int qq = pos + k - 10; if (qq>=0 && qq<TENC) s2 += sm[L_WF+c*SK+k]*sm[L_AL+qq]; }
        sm[L_FS + c*TENC + pos] = s2;
      }
    } else if (tid < 872){
      if (t >= 1){
        const int col = tid - 712;
        float a0=0.f, a1=0.f, a2=0.f, a3=0.f;
        #pragma unroll 4
        for (int kk = 0; kk < 64; kk += 4){
          const float* xp0 = (kk   < 32) ? (sm + L_H2 + 8*kk)        : (sm + L_CTX + 8*kk - 256);
          const float* xp1 = (kk+1 < 32) ? (sm + L_H2 + 8*(kk+1))    : (sm + L_CTX + 8*(kk+1) - 256);
          const float* xp2 = (kk+2 < 32) ? (sm + L_H2 + 8*(kk+2))    : (sm + L_CTX + 8*(kk+2) - 256);
          const float* xp3 = (kk+3 < 32) ? (sm + L_H2 + 8*(kk+3))    : (sm + L_CTX + 8*(kk+3) - 256);
          uint4 w0 = *(const uint4*)(P5 + (unsigned)(kk  )*1280u + col*8u);
          uint4 w1 = *(const uint4*)(P5 + (unsigned)(kk+1)*1280u + col*8u);
          uint4 w2 = *(const uint4*)(P5 + (unsigned)(kk+2)*1280u + col*8u);
          uint4 w3 = *(const uint4*)(P5 + (unsigned)(kk+3)*1280u + col*8u);
          FMA8S(w0, *(const float4*)xp0, *(const float4*)(xp0+4), a0)
          FMA8S(w1, *(const float4*)xp1, *(const float4*)(xp1+4), a1)
          FMA8S(w2, *(const float4*)xp2, *(const float4*)(xp2+4), a2)
          FMA8S(w3, *(const float4*)xp3, *(const float4*)(xp3+4), a3)
        }
        const int m = col >> 1, r = col & 1;
        out[(unsigned)b*NMELS*TMELS + m*TMELS + 2*(t-1) + r] = (a0+a1)+(a2+a3) + acb[col];
      }
    }
    __syncthreads();
    // 5. q = tanh
    if (tid < AD) sm[L_QS+tid] = tanhf(attWb[tid] + sm[L_P4+tid] + sm[L_P4+128+tid] + sm[L_P4+256+tid] + sm[L_P4+384+tid]);
    __syncthreads();
    // 6. G = attV @ q
    if (tid < DF*DK){
      float a = 0.f;
      for (int k = 0; k < AD; k++) a += sm[L_QS+k]*__uint_as_float(((unsigned)avth[k*(DF*DK)+tid])<<16);
      sm[L_GS+tid] = a;
    }
    __syncthreads();
    // 7. e[pos] (4 threads/pos)
    if (tid < 4*TENC){
      const int pos = tid >> 2, qr = tid & 3;
      float g[DF];
      #pragma unroll
      for (int c=0;c<DF;c++){
        float s=0.f;
        #pragma unroll
        for (int k=0;k<DK;k++){
          int q2 = pos + k - 10;
          if (q2>=0 && q2<TENC) s += sm[L_AL+q2]*sm[L_GS+c*DK+k];
        }
        g[c]=s;
      }
      float fv[SF];
      #pragma unroll
      for (int s2=0;s2<SF;s2++) fv[s2] = sm[L_FS + s2*TENC + pos];
      float pp = 0.f;
      for (int h = qr*32; h < qr*32+32; h++){
        float u = attTb[h];
        #pragma unroll
        for (int s2=0;s2<SF;s2++) u += attU[h*SF+s2]*fv[s2];
        #pragma unroll
        for (int c=0;c<DF;c++) u += attT[h*DF+c]*g[c];
        pp += attv[h]*tanh_fast(u);
      }
      pp += __shfl_xor(pp,1);
      pp += __shfl_xor(pp,2);
      if (qr==0) sm[L_ES+pos] = pp + sm[L_PS+pos];
    }
    __syncthreads();
    // 8. softmax over 200 — single wave (wave 0), no internal barriers
    if (tid < 64){
      float v0 = sm[L_ES+tid], v1 = sm[L_ES+64+tid], v2 = sm[L_ES+128+tid];
      float v3 = (tid < 8) ? sm[L_ES+192+tid] : -3.0e38f;
      float mx = fmaxf(fmaxf(v0,v1), fmaxf(v2,v3));
      for (int o=1;o<64;o<<=1) mx = fmaxf(mx, __shfl_xor(mx,o));
      float e0 = expf(v0-mx), e1 = expf(v1-mx), e2 = expf(v2-mx);
      float e3 = (tid < 8) ? expf(v3-mx) : 0.f;
      float sv = ((e0+e1)+(e2+e3));
      for (int o=1;o<64;o<<=1) sv += __shfl_xor(sv,o);
      float inv = 1.f/sv;
      float a0 = e0*inv, a1 = e1*inv, a2 = e2*inv;
      sm[L_AL+tid] = a0; sm[L_AL+64+tid] = a1; sm[L_AL+128+tid] = a2;
      unsigned ob = 1024000u + (unsigned)b*TENC*STEPS + (unsigned)t;
      out[ob + (unsigned)tid*STEPS]       = a0;
      out[ob + (unsigned)(64+tid)*STEPS]  = a1;
      out[ob + (unsigned)(128+tid)*STEPS] = a2;
      if (tid < 8){
        float a3 = e3*inv;
        sm[L_AL+192+tid] = a3;
        out[ob + (unsigned)(192+tid)*STEPS] = a3;
      }
    }
    __syncthreads();
    // 9. ctx partials (bf16 memory, cached)
    {
      const int grp2 = tid >> 7, jp = tid & 127;
      const unsigned base = ((unsigned)b*TENC)*128u + jp;
      float a0 = 0.f, a1 = 0.f;
      for (int p = grp2*25; p < grp2*25+25; p++){
        unsigned u = memh[base + (unsigned)p*128u];
        float al = sm[L_AL+p];
        a0 += al*__uint_as_float(u << 16);
        a1 += al*__uint_as_float(u & 0xffff0000u);
      }
      sm[L_P4 + grp2*256 + 2*jp    ] = a0;
      sm[L_P4 + grp2*256 + 2*jp + 1] = a1;
    }
    __syncthreads();
    // 9b. ctx reduce + build xS2 = [h1 | ctx | h2]
    if (tid < 256){
      float c = 0.f;
      #pragma unroll
      for (int g2 = 0; g2 < 8; g2++) c += sm[L_P4 + g2*256 + tid];
      sm[L_CTX+tid] = c;
      sm[L_XS+256+tid] = c;
    } else if (tid < 512){
      sm[L_XS + (tid-256)] = sm[L_H1 + (tid-256)];
    } else if (tid < 768){
      sm[L_XS + tid] = sm[L_H2 + (tid-512)];
    }
    __syncthreads();
    // 10. LSTM2 partials
    {
      const float* xq = sm + L_XS + 192*q;
      const unsigned short* Wq = Q2 + (unsigned)q*196608u;
      float a0=0.f, a1=0.f, a2=0.f, a3=0.f;
      #pragma unroll 4
      for (int kk = 0; kk < 24; kk++){
        float4 xa = *(const float4*)(xq + 8*kk);
        float4 xb = *(const float4*)(xq + 8*kk + 4);
        const unsigned short* wr = Wq + (unsigned)kk*8192u + c0*8u;
        uint4 w0 = *(const uint4*)(wr);
        uint4 w1 = *(const uint4*)(wr + 2048);
        uint4 w2 = *(const uint4*)(wr + 4096);
        uint4 w3 = *(const uint4*)(wr + 6144);
        FMA8S(w0, xa, xb, a0)
        FMA8S(w1, xa, xb, a1)
        FMA8S(w2, xa, xb, a2)
        FMA8S(w3, xa, xb, a3)
      }
      sm[L_P4 + q*1024 + c0      ] = a0;
      sm[L_P4 + q*1024 + c0 + 256] = a1;
      sm[L_P4 + q*1024 + c0 + 512] = a2;
      sm[L_P4 + q*1024 + c0 + 768] = a3;
    }
    __syncthreads();
    // 11. LSTM2 update || build xS1(t+1) || prefetch pre(t+1)
    if (tid < 256){
      float g[4];
      #pragma unroll
      for (int gg2 = 0; gg2 < 4; gg2++){
        int col = gg2*256 + tid;
        g[gg2] = sm[L_B2+col] + sm[L_P4+col] + sm[L_P4+1024+col] + sm[L_P4+2048+col] + sm[L_P4+3072+col];
      }
      float c = sigm(g[1])*sm[L_C2+tid] + sigm(g[0])*tanhf(g[2]);
      sm[L_C2+tid] = c;
      sm[L_H2+tid] = sigm(g[3])*tanhf(c);
    } else if (tid < 384){
      if (t+1 < STEPS)
        sm[L_XS+tid] = __builtin_nontemporal_load(&ws[WS_PRE2 + ((unsigned)(t+1)*BB + b)*PRE2N + (tid-256)]);
    } else if (tid < 640){
      sm[L_XS+tid] = sm[L_H1 + (tid-384)];     // h1 part of xS1(t+1)
    } else if (tid < 896){
      sm[L_XS + (tid-640)] = sm[L_CTX + (tid-640)];  // ctx part of xS1(t+1)
    }
    __syncthreads();
  }
  // epilogue: proj for t = STEPS-1 (h2/ctx are final-step values)
  if (tid < 160){
    const int col = tid;
    float a0=0.f, a1=0.f, a2=0.f, a3=0.f;
    #pragma unroll 4
    for (int kk = 0; kk < 64; kk += 4){
      const float* xp0 = (kk   < 32) ? (sm + L_H2 + 8*kk)     : (sm + L_CTX + 8*kk - 256);
      const float* xp1 = (kk+1 < 32) ? (sm + L_H2 + 8*(kk+1)) : (sm + L_CTX + 8*(kk+1) - 256);
      const float* xp2 = (kk+2 < 32) ? (sm + L_H2 + 8*(kk+2)) : (sm + L_CTX + 8*(kk+2) - 256);
      const float* xp3 = (kk+3 < 32) ? (sm + L_H2 + 8*(kk+3)) : (sm + L_CTX + 8*(kk+3) - 256);
      uint4 w0 = *(const uint4*)(P5 + (unsigned)(kk  )*1280u + col*8u);
      uint4 w1 = *(const uint4*)(P5 + (unsigned)(kk+1)*1280u + col*8u);
      uint4 w2 = *(const uint4*)(P5 + (unsigned)(kk+2)*1280u + col*8u);
      uint4 w3 = *(const uint4*)(P5 + (unsigned)(kk+3)*1280u + col*8u);
      FMA8S(w0, *(const float4*)xp0, *(const float4*)(xp0+4), a0)
      FMA8S(w1, *(const float4*)xp1, *(const float4*)(xp1+4), a1)
      FMA8S(w2, *(const float4*)xp2, *(const float4*)(xp2+4), a2)
      FMA8S(w3, *(const float4*)xp3, *(const float4*)(xp3+4), a3)
    }
    const int m = col >> 1, r = col & 1;
    out[(unsigned)b*NMELS*TMELS + m*TMELS + 2*(STEPS-1) + r] = (a0+a1)+(a2+a3) + acb[col];
  }
}

extern "C" void kernel_launch(void* const* d_in, const int* in_sizes, int n_in,
                              void* d_out, int out_size, void* d_ws, size_t ws_size,
                              hipStream_t stream) {
  (void)in_sizes; (void)n_in; (void)out_size; (void)ws_size;
  const float* mels   = (const float*)d_in[0];
  const float* memory = (const float*)d_in[1];
  const float* pre_W1 = (const float*)d_in[2];
  const float* pre_b1 = (const float*)d_in[3];
  const float* pre_W2 = (const float*)d_in[4];
  const float* pre_b2 = (const float*)d_in[5];
  const float* al_Wih = (const float*)d_in[6];
  const float* al_Whh = (const float*)d_in[7];
  const float* al_bih = (const float*)d_in[8];
  const float* al_bhh = (const float*)d_in[9];
  const float* att_W  = (const float*)d_in[10];
  const float* att_Wb = (const float*)d_in[11];
  const float* att_V  = (const float*)d_in[12];
  const float* att_F  = (const float*)d_in[13];
  const float* att_U  = (const float*)d_in[14];
  const float* att_T  = (const float*)d_in[15];
  const float* att_Tb = (const float*)d_in[16];
  const float* att_v  = (const float*)d_in[17];
  const float* prior  = (const float*)d_in[18];
  const float* dl_Wih = (const float*)d_in[19];
  const float* dl_Whh = (const float*)d_in[20];
  const float* dl_bih = (const float*)d_in[21];
  const float* dl_bhh = (const float*)d_in[22];
  const float* ac_W   = (const float*)d_in[23];
  const float* ac_b   = (const float*)d_in[24];
  float* ws  = (float*)d_ws;
  unsigned short* hw = (unsigned short*)d_ws;
  float* out = (float*)d_out;

  hipFuncSetAttribute((const void*)decoder, hipFuncAttributeMaxDynamicSharedMemorySize, DYNB);

  auto TR = [&](const float* src, unsigned off, int R, int C){
    int n = R*C;
    trk<<<dim3((n+255)/256), dim3(256), 0, stream>>>(src, ws + off, R, C);
  };
  pkq1c<<<dim3((1024*640+255)/256), dim3(256), 0, stream>>>(al_Wih, al_Whh, hw + QW1);
  pkq2c<<<dim3((1024*768+255)/256), dim3(256), 0, stream>>>(dl_Wih, dl_Whh, hw + QW2);
  pk8h<<<dim3((160*512+255)/256), dim3(256), 0, stream>>>(ac_W, hw + HP5, 160, 512);
  TR(att_W,  WS_ATTWT, 128, 256);
  TR(pre_W1, WS_PW1T,  256, 80);
  TR(pre_W2, WS_PW2T,  128, 256);
  {
    int n = BB*TENC*MEM;
    pkmem<<<dim3((n+255)/256), dim3(256), 0, stream>>>(memory, (unsigned short*)(ws + WS_MEMH), n);
  }
  pkavt<<<dim3((128*168+255)/256), dim3(256), 0, stream>>>(att_V, (unsigned short*)(ws + WS_AVTH));

  prenetk<<<dim3(STEPS), dim3(256), 0, stream>>>(mels, pre_b1, pre_b2, ws);

  decoder<<<dim3(BB), dim3(BLK), DYNB, stream>>>(
      al_bih, al_bhh, dl_bih, dl_bhh, prior, att_F,
      att_Wb, att_U, att_T, att_Tb, att_v,
      ac_b, ws, out);
}